// Round 6
// baseline (343.785 us; speedup 1.0000x reference)
//
#include <hip/hip_runtime.h>

#define NROWS 16384
#define KCODES 8192
#define DDIM 256
#define MARGIN 2.0f
#define BLKLIST 768

typedef __attribute__((ext_vector_type(8))) short short8;
typedef __attribute__((ext_vector_type(4))) float f32x4;

// ---------------- helpers ----------------
__device__ inline unsigned short f2bf(float x) {
    unsigned u = __float_as_uint(x);
    return (unsigned short)((u + 0x7FFFu + ((u >> 16) & 1u)) >> 16);  // RNE
}

__device__ inline void gload16(const void* g, void* l) {
    __builtin_amdgcn_global_load_lds(
        (const __attribute__((address_space(1))) unsigned char*)g,
        (__attribute__((address_space(3))) unsigned char*)l, 16, 0, 0);
}

__device__ inline void exact_rescore(const float* __restrict__ z, const float* __restrict__ cb,
                                     const float* __restrict__ z2g, const float* __restrict__ e2g,
                                     int grow, int gcol, unsigned long long* best) {
    const float4* av = reinterpret_cast<const float4*>(z + (size_t)grow * DDIM);
    const float4* bv = reinterpret_cast<const float4*>(cb + (size_t)gcol * DDIM);
    float dot = 0.f;
    #pragma unroll 8
    for (int j = 0; j < 64; ++j) {
        const float4 xa = av[j], xb = bv[j];
        dot = fmaf(xa.x, xb.x, fmaf(xa.y, xb.y, fmaf(xa.z, xb.z, fmaf(xa.w, xb.w, dot))));
    }
    const float de = z2g[grow] + e2g[gcol] - 2.0f * dot;
    const unsigned long long key =
        ((unsigned long long)__float_as_uint(de) << 32) | (unsigned)gcol;
    atomicMin(best + grow, key);
}

// ---------------- convert fp32 -> bf16 pre-tiled fragment layout + fused sumsq ----------------
// chunk (g, kb2): 1 KB, slot s: row g*16 + (s&15), k = kb2*32 + (s>>4)*8 .. +8
__global__ __launch_bounds__(256) void k_convert(
    const float* __restrict__ in, unsigned short* __restrict__ outt,
    float* __restrict__ sumsq, int ngroups,
    unsigned long long* best, unsigned* amin, float* accum, unsigned* counter)
{
    const int tid = threadIdx.x;
    if (best != nullptr) {
        const int gid = blockIdx.x * 256 + tid;
        if (gid < NROWS) { best[gid] = 0xFFFFFFFFFFFFFFFFull; amin[gid] = 0x7F800000u; }
        if (gid == 0) { accum[0] = 0.0f; counter[0] = 0u; }
    }
    const int g = blockIdx.x * 4 + (tid >> 6);
    const int lane = tid & 63;
    if (g >= ngroups) return;
    const int row = g * 16 + (lane & 15);
    const int ko = (lane >> 4) * 8;
    float ss = 0.f;
    #pragma unroll
    for (int kb2 = 0; kb2 < 8; ++kb2) {
        const float4* src = reinterpret_cast<const float4*>(in + (size_t)row * DDIM + kb2 * 32 + ko);
        const float4 a = src[0], b = src[1];
        ss += a.x * a.x + a.y * a.y + a.z * a.z + a.w * a.w
            + b.x * b.x + b.y * b.y + b.z * b.z + b.w * b.w;
        short8 p;
        p[0] = (short)f2bf(a.x); p[1] = (short)f2bf(a.y); p[2] = (short)f2bf(a.z); p[3] = (short)f2bf(a.w);
        p[4] = (short)f2bf(b.x); p[5] = (short)f2bf(b.y); p[6] = (short)f2bf(b.z); p[7] = (short)f2bf(b.w);
        *reinterpret_cast<short8*>(outt + (((size_t)(g * 8 + kb2)) << 9) + lane * 8) = p;
    }
    ss += __shfl_xor(ss, 16);
    ss += __shfl_xor(ss, 32);
    if (lane < 16) sumsq[g * 16 + lane] = ss;
}

// ---------------- MFMA screen (256x256 tile, 8 waves): emit near-min candidates ----------------
__global__ __launch_bounds__(512, 2) void k_screen(
    const float* __restrict__ z, const float* __restrict__ cbp,
    const unsigned short* __restrict__ z_t, const unsigned short* __restrict__ cb_t,
    const float* __restrict__ z2g, const float* __restrict__ e2g,
    unsigned* amin, unsigned long long* best,
    unsigned* counter, unsigned* list, unsigned C)
{
    // double-buffered: buf b at ldsb + b*65536; A chunks at +0 (32 KB), B at +32768
    __shared__ __align__(16) short lds[65536];   // 128 KB
    char* ldsb = (char*)lds;
    __shared__ unsigned gbase_s;

    const int tid = threadIdx.x;
    const int lane = tid & 63;
    const int wave = tid >> 6;     // 0..7
    const int wm = wave & 1;       // row-half
    const int wn = wave >> 1;      // col-quarter 0..3
    const int lhi = lane >> 4;
    const int llo = lane & 15;

    const int bx = blockIdx.x;     // 2048 blocks = 64 rt x 32 ct
    const int st = bx >> 6;        // 0..31
    const int wi = bx & 63;
    const int rt = (st & 7) * 8 + (wi >> 3);   // 0..63
    const int ct = (st >> 3) * 8 + (wi & 7);   // 0..31
    const int row0 = rt * 256;
    const int col0 = ct * 256;

    f32x4 acc[8][4];
    const f32x4 zero = {0.f, 0.f, 0.f, 0.f};
    #pragma unroll
    for (int i = 0; i < 8; ++i)
        #pragma unroll
        for (int j = 0; j < 4; ++j) acc[i][j] = zero;

    // stage K-step ks (64 k) into buffer b: 32 A-chunks + 32 B-chunks, 1 KB each.
    // chunk c: rg = c>>1 (row-group in tile), kk = c&1 (32-k half). wave stages c = wave*4..+3.
    auto STAGE = [&](int b, int ks) {
        char* buf = ldsb + b * 65536;
        #pragma unroll
        for (int i = 0; i < 4; ++i) {
            const int c = wave * 4 + i;            // 0..31
            const int kb2 = ks * 2 + (c & 1);
            const int g_a = rt * 16 + (c >> 1);
            gload16((const char*)z_t + (((size_t)(g_a * 8 + kb2)) << 10) + lane * 16,
                    buf + c * 1024);
            const int g_b = ct * 16 + (c >> 1);
            gload16((const char*)cb_t + (((size_t)(g_b * 8 + kb2)) << 10) + lane * 16,
                    buf + 32768 + c * 1024);
        }
    };

    STAGE(0, 0);
    __syncthreads();   // vmcnt drained -> buf0 ready
    #pragma unroll
    for (int ks = 0; ks < 4; ++ks) {
        const int cur = ks & 1;
        if (ks < 3) STAGE(cur ^ 1, ks + 1);   // issue next-tile loads BEFORE compute
        char* buf = ldsb + cur * 65536;
        #pragma unroll
        for (int kk = 0; kk < 2; ++kk) {
            short8 bfr[4];
            #pragma unroll
            for (int fn = 0; fn < 4; ++fn) {
                const int cc = ((wn * 4 + fn) * 2) + kk;
                bfr[fn] = *reinterpret_cast<const short8*>(buf + 32768 + cc * 1024 + lane * 16);
            }
            #pragma unroll
            for (int fm = 0; fm < 8; ++fm) {
                const int ca = ((wm * 8 + fm) * 2) + kk;
                const short8 af = *reinterpret_cast<const short8*>(buf + ca * 1024 + lane * 16);
                #pragma unroll
                for (int fn = 0; fn < 4; ++fn)
                    acc[fm][fn] = __builtin_amdgcn_mfma_f32_16x16x32_bf16(af, bfr[fn], acc[fm][fn], 0, 0, 0);
            }
        }
        __syncthreads();   // readers of buf[cur] done + next tile's loads landed
    }

    // ---- epilogue (overlays buffer 0) ----
    float* rowmin = (float*)ldsb;            // [4][256]  (per wn-quarter, per local row)
    float* thrbuf = (float*)(ldsb + 4096);   // [256]
    unsigned* lcnt = (unsigned*)(ldsb + 5120);
    unsigned* llist = (unsigned*)(ldsb + 5136);   // BLKLIST entries

    if (tid == 0) *lcnt = 0u;
    const int cbase = col0 + wn * 64;
    float e2c[4];
    #pragma unroll
    for (int fn = 0; fn < 4; ++fn) e2c[fn] = e2g[cbase + fn * 16 + llo];

    // pass 1: per-row min over this wave's 64-col quarter
    #pragma unroll
    for (int fm = 0; fm < 8; ++fm) {
        #pragma unroll
        for (int rg = 0; rg < 4; ++rg) {
            const int rl_ = wm * 128 + fm * 16 + lhi * 4 + rg;
            const float z2v = z2g[row0 + rl_];
            float m = z2v + e2c[0] - 2.0f * acc[fm][0][rg];
            #pragma unroll
            for (int fn = 1; fn < 4; ++fn)
                m = fminf(m, z2v + e2c[fn] - 2.0f * acc[fm][fn][rg]);
            #pragma unroll
            for (int off = 1; off < 16; off <<= 1) m = fminf(m, __shfl_xor(m, off));
            if (llo == 0) rowmin[wn * 256 + rl_] = m;
        }
    }
    __syncthreads();
    if (tid < 256) {
        float m2 = rowmin[tid];
        #pragma unroll
        for (int q = 1; q < 4; ++q) m2 = fminf(m2, rowmin[q * 256 + tid]);
        const unsigned cur = amin[row0 + tid];
        unsigned old = cur;
        if (__float_as_uint(m2) < cur) old = atomicMin(&amin[row0 + tid], __float_as_uint(m2));
        thrbuf[tid] = fminf(__uint_as_float(old), m2) + MARGIN;
    }
    __syncthreads();

    // pass 2: emit candidates
    #pragma unroll
    for (int fm = 0; fm < 8; ++fm) {
        #pragma unroll
        for (int rg = 0; rg < 4; ++rg) {
            const int rl_ = wm * 128 + fm * 16 + lhi * 4 + rg;
            const int grow = row0 + rl_;
            const float z2v = z2g[grow];
            const float thr = thrbuf[rl_];
            #pragma unroll
            for (int fn = 0; fn < 4; ++fn) {
                const float d = z2v + e2c[fn] - 2.0f * acc[fm][fn][rg];
                if (d <= thr) {
                    const unsigned v = ((unsigned)grow << 13) | (unsigned)(cbase + fn * 16 + llo);
                    const unsigned slot = atomicAdd(lcnt, 1u);
                    if (slot < BLKLIST) llist[slot] = v;
                    else exact_rescore(z, cbp, z2g, e2g, grow, v & 8191u, best);
                }
            }
        }
    }
    __syncthreads();
    const unsigned bc = min(*lcnt, (unsigned)BLKLIST);
    if (tid == 0 && bc) gbase_s = atomicAdd(counter, bc);
    __syncthreads();
    for (unsigned i = tid; i < bc; i += 512) {
        const unsigned v = llist[i];
        const unsigned slot = gbase_s + i;
        if (slot < C) list[slot] = v;
        else exact_rescore(z, cbp, z2g, e2g, (int)(v >> 13), (int)(v & 8191u), best);
    }
}

// ---------------- exact rescore of candidate list (wave per candidate) ----------------
__global__ __launch_bounds__(256) void k_rescore(
    const float* __restrict__ z, const float* __restrict__ cbp,
    const float* __restrict__ z2g, const float* __restrict__ e2g,
    const unsigned* __restrict__ list, const unsigned* __restrict__ counter, unsigned C,
    unsigned long long* best)
{
    const unsigned n = min(counter[0], C);
    const unsigned wid = (blockIdx.x * blockDim.x + threadIdx.x) >> 6;
    const unsigned nw = (gridDim.x * blockDim.x) >> 6;
    const int lane = threadIdx.x & 63;
    for (unsigned i = wid; i < n; i += nw) {
        const unsigned v = list[i];
        const unsigned row = v >> 13, col = v & 8191u;
        const float4 a = *reinterpret_cast<const float4*>(z + (size_t)row * DDIM + lane * 4);
        const float4 b = *reinterpret_cast<const float4*>(cbp + (size_t)col * DDIM + lane * 4);
        float s = fmaf(a.x, b.x, fmaf(a.y, b.y, fmaf(a.z, b.z, a.w * b.w)));
        #pragma unroll
        for (int off = 1; off < 64; off <<= 1) s += __shfl_xor(s, off);
        if (lane == 0) {
            const float de = z2g[row] + e2g[col] - 2.0f * s;
            const unsigned long long key =
                ((unsigned long long)__float_as_uint(de) << 32) | col;
            atomicMin(&best[row], key);
        }
    }
}

// ---------------- gather + z_st + loss ----------------
__global__ __launch_bounds__(1024) void k_gather(
    const float* __restrict__ z, const float* __restrict__ cbp,
    const unsigned long long* __restrict__ best,
    float* __restrict__ out, float* __restrict__ accum)
{
    __shared__ float wsum[16];
    const int tid = threadIdx.x;
    const int row = blockIdx.x * 16 + (tid >> 6);
    const int lane = tid & 63;
    const unsigned k = (unsigned)(best[row] & 0xFFFFFFFFull);
    const float4 ze = *reinterpret_cast<const float4*>(z + (size_t)row * DDIM + lane * 4);
    const float4 cq = *reinterpret_cast<const float4*>(cbp + (size_t)k * DDIM + lane * 4);
    float4 zst;
    zst.x = ze.x + (cq.x - ze.x); zst.y = ze.y + (cq.y - ze.y);
    zst.z = ze.z + (cq.z - ze.z); zst.w = ze.w + (cq.w - ze.w);
    *reinterpret_cast<float4*>(out + (size_t)row * DDIM + lane * 4) = zst;
    const float dx = cq.x - ze.x, dy = cq.y - ze.y, dz = cq.z - ze.z, dw = cq.w - ze.w;
    float s = dx * dx + dy * dy + dz * dz + dw * dw;
    #pragma unroll
    for (int off = 32; off > 0; off >>= 1) s += __shfl_down(s, off);
    if (lane == 0) {
        wsum[tid >> 6] = s;
        out[(size_t)NROWS * DDIM + row] = (float)k;
    }
    __syncthreads();
    if (tid == 0) {
        float tot = 0.f;
        #pragma unroll
        for (int i = 0; i < 16; ++i) tot += wsum[i];
        atomicAdd(accum, tot);
    }
}

// ---------------- final scalars ----------------
__global__ void k_final(const float* __restrict__ accum, float* __restrict__ out) {
    const float m = accum[0] / (float)(NROWS * DDIM);
    out[(size_t)NROWS * DDIM + NROWS + 0] = m;
    out[(size_t)NROWS * DDIM + NROWS + 1] = m;
}

extern "C" void kernel_launch(void* const* d_in, const int* in_sizes, int n_in,
                              void* d_out, int out_size, void* d_ws, size_t ws_size,
                              hipStream_t stream)
{
    const float* z  = (const float*)d_in[0];
    const float* cb = (const float*)d_in[1];
    float* out = (float*)d_out;

    // bf16 pre-tiled scratch lives in d_out's z_st region (12 MB of 16.8 MB),
    // consumed by k_screen and fully overwritten afterwards by k_gather.
    unsigned short* z_t  = (unsigned short*)d_out;                      // 8 MB
    unsigned short* cb_t = (unsigned short*)((char*)d_out + 8388608);   // 4 MB

    char* ws = (char*)d_ws;
    unsigned long long* best = (unsigned long long*)ws;            // 131072 B
    unsigned* amin = (unsigned*)(ws + 131072);                     // 65536 B
    float* e2    = (float*)(ws + 131072 + 65536);                  // 32768 B
    float* z2    = (float*)(ws + 131072 + 65536 + 32768);          // 65536 B
    float* accum   = (float*)(ws + 294912);
    unsigned* counter = (unsigned*)(ws + 294916);
    unsigned* list = (unsigned*)(ws + 295936);
    unsigned C = 0;
    if (ws_size > 295936 + 16) {
        size_t c = (ws_size - 295936) / 4;
        if (c > 4194304) c = 4194304;
        C = (unsigned)c;
    }

    k_convert<<<NROWS / 16 / 4, 256, 0, stream>>>(z, z_t, z2, NROWS / 16, best, amin, accum, counter);
    k_convert<<<KCODES / 16 / 4, 256, 0, stream>>>(cb, cb_t, e2, KCODES / 16, nullptr, nullptr, nullptr, nullptr);
    k_screen<<<2048, 512, 0, stream>>>(z, cb, z_t, cb_t, z2, e2, amin, best, counter, list, C);
    k_rescore<<<1024, 256, 0, stream>>>(z, cb, z2, e2, list, counter, C, best);
    k_gather<<<NROWS / 16, 1024, 0, stream>>>(z, cb, best, out, accum);
    k_final<<<1, 1, 0, stream>>>(accum, out);
}

// Round 7
// 253.332 us; speedup vs baseline: 1.3570x; 1.3570x over previous
//
#include <hip/hip_runtime.h>

#define NROWS 16384
#define KCODES 8192
#define DDIM 256
#define MARGIN 2.0f
#define BLKLIST 768
#define NCI 16   // col-tiles swept per block

typedef __attribute__((ext_vector_type(8))) short short8;
typedef __attribute__((ext_vector_type(4))) float f32x4;

// ---------------- helpers ----------------
__device__ inline unsigned short f2bf(float x) {
    unsigned u = __float_as_uint(x);
    return (unsigned short)((u + 0x7FFFu + ((u >> 16) & 1u)) >> 16);  // RNE
}

__device__ inline void gload16(const void* g, void* l) {
    __builtin_amdgcn_global_load_lds(
        (const __attribute__((address_space(1))) unsigned char*)g,
        (__attribute__((address_space(3))) unsigned char*)l, 16, 0, 0);
}

__device__ inline void exact_rescore(const float* __restrict__ z, const float* __restrict__ cb,
                                     const float* __restrict__ z2g, const float* __restrict__ e2g,
                                     int grow, int gcol, unsigned long long* best) {
    const float4* av = reinterpret_cast<const float4*>(z + (size_t)grow * DDIM);
    const float4* bv = reinterpret_cast<const float4*>(cb + (size_t)gcol * DDIM);
    float dot = 0.f;
    #pragma unroll 8
    for (int j = 0; j < 64; ++j) {
        const float4 xa = av[j], xb = bv[j];
        dot = fmaf(xa.x, xb.x, fmaf(xa.y, xb.y, fmaf(xa.z, xb.z, fmaf(xa.w, xb.w, dot))));
    }
    const float de = z2g[grow] + e2g[gcol] - 2.0f * dot;
    const unsigned long long key =
        ((unsigned long long)__float_as_uint(de) << 32) | (unsigned)gcol;
    atomicMin(best + grow, key);
}

// ---------------- convert fp32 -> bf16 pre-tiled fragment layout + fused sumsq ----------------
// chunk (g, kb2): 1 KB, slot s: row g*16 + (s&15), k = kb2*32 + (s>>4)*8 .. +8
__global__ __launch_bounds__(256) void k_convert(
    const float* __restrict__ in, unsigned short* __restrict__ outt,
    float* __restrict__ sumsq, int ngroups,
    unsigned long long* best, unsigned* amin, float* accum, unsigned* counter)
{
    const int tid = threadIdx.x;
    if (best != nullptr) {
        const int gid = blockIdx.x * 256 + tid;
        if (gid < NROWS) { best[gid] = 0xFFFFFFFFFFFFFFFFull; amin[gid] = 0x7F800000u; }
        if (gid == 0) { accum[0] = 0.0f; counter[0] = 0u; }
    }
    const int g = blockIdx.x * 4 + (tid >> 6);
    const int lane = tid & 63;
    if (g >= ngroups) return;
    const int row = g * 16 + (lane & 15);
    const int ko = (lane >> 4) * 8;
    float ss = 0.f;
    #pragma unroll
    for (int kb2 = 0; kb2 < 8; ++kb2) {
        const float4* src = reinterpret_cast<const float4*>(in + (size_t)row * DDIM + kb2 * 32 + ko);
        const float4 a = src[0], b = src[1];
        ss += a.x * a.x + a.y * a.y + a.z * a.z + a.w * a.w
            + b.x * b.x + b.y * b.y + b.z * b.z + b.w * b.w;
        short8 p;
        p[0] = (short)f2bf(a.x); p[1] = (short)f2bf(a.y); p[2] = (short)f2bf(a.z); p[3] = (short)f2bf(a.w);
        p[4] = (short)f2bf(b.x); p[5] = (short)f2bf(b.y); p[6] = (short)f2bf(b.z); p[7] = (short)f2bf(b.w);
        *reinterpret_cast<short8*>(outt + (((size_t)(g * 8 + kb2)) << 9) + lane * 8) = p;
    }
    ss += __shfl_xor(ss, 16);
    ss += __shfl_xor(ss, 32);
    if (lane < 16) sumsq[g * 16 + lane] = ss;
}

// ---------------- MFMA screen: 128-row band, A resident, sweep 16 col-tiles ----------------
// LDS: A[0,65536) 64 chunks (gl*8+kb2)*1024 | B buf b at 65536+b*32768, chunk (cl*2+kk)*1024
//      escr at 131072: rowmin[4][128] f | thrbuf[128] f | lcnt | llist[BLKLIST]
__global__ __launch_bounds__(512, 2) void k_screen(
    const float* __restrict__ z, const float* __restrict__ cbp,
    const unsigned short* __restrict__ z_t, const unsigned short* __restrict__ cb_t,
    const float* __restrict__ z2g, const float* __restrict__ e2g,
    unsigned* amin, unsigned long long* best,
    unsigned* counter, unsigned* list, unsigned C)
{
    __shared__ __align__(16) char smem[136720];
    char* ldsA = smem;
    char* ldsB = smem + 65536;
    char* escr = smem + 131072;
    __shared__ unsigned gbase_s;

    const int tid = threadIdx.x;
    const int lane = tid & 63;
    const int wave = tid >> 6;     // 0..7
    const int wm = wave & 1;       // 64-row half
    const int wn = wave >> 1;      // 64-col quarter
    const int lhi = lane >> 4;
    const int llo = lane & 15;

    const int bx = blockIdx.x;     // 256 blocks
    const int rt = bx & 127;       // row band (128 rows)
    const int cgrp = bx >> 7;      // 0..1
    const int row0 = rt * 128;

    // stage A band once: 64 chunks of 1 KB, wave stages 8
    #pragma unroll
    for (int i = 0; i < 8; ++i) {
        const int c = wave * 8 + i;                 // gl = c>>3, kb2 = c&7
        gload16((const char*)z_t + (((size_t)((rt * 8 + (c >> 3)) * 8 + (c & 7))) << 10) + lane * 16,
                ldsA + c * 1024);
    }

    auto STAGE_B = [&](int b, int ct_, int ks) {
        char* buf = ldsB + b * 32768;
        #pragma unroll
        for (int i = 0; i < 4; ++i) {
            const int c = wave * 4 + i;             // cl = c>>1, kk = c&1
            const int gb = (ct_ * 16 + (c >> 1)) * 8 + ks * 2 + (c & 1);
            gload16((const char*)cb_t + ((size_t)gb << 10) + lane * 16, buf + c * 1024);
        }
    };

    STAGE_B(0, cgrp * NCI, 0);
    __syncthreads();   // A band + first B tile ready (vmcnt drained)

    // hoist z2 for my 16 rows into registers
    float z2r[4][4];
    #pragma unroll
    for (int fm = 0; fm < 4; ++fm)
        #pragma unroll
        for (int rg = 0; rg < 4; ++rg)
            z2r[fm][rg] = z2g[row0 + wm * 64 + fm * 16 + lhi * 4 + rg];

    float* rowmin = (float*)escr;               // [4][128]
    float* thrbuf = (float*)(escr + 2048);      // [128]
    unsigned* lcnt = (unsigned*)(escr + 2560);
    unsigned* llist = (unsigned*)(escr + 2576); // BLKLIST

    #pragma unroll 1
    for (int ci = 0; ci < NCI; ++ci) {
        const int ct = cgrp * NCI + ci;
        const int col0 = ct * 256;

        f32x4 acc[4][4];
        const f32x4 zero = {0.f, 0.f, 0.f, 0.f};
        #pragma unroll
        for (int i = 0; i < 4; ++i)
            #pragma unroll
            for (int j = 0; j < 4; ++j) acc[i][j] = zero;

        #pragma unroll
        for (int ks = 0; ks < 4; ++ks) {
            const int cur = ks & 1;
            if (ks < 3) STAGE_B(cur ^ 1, ct, ks + 1);
            else if (ci != NCI - 1) STAGE_B(0, ct + 1, 0);   // cross-iter prefetch
            char* bufB = ldsB + cur * 32768;
            #pragma unroll
            for (int kk = 0; kk < 2; ++kk) {
                short8 bfr[4];
                #pragma unroll
                for (int fn = 0; fn < 4; ++fn)
                    bfr[fn] = *reinterpret_cast<const short8*>(
                        bufB + (((wn * 4 + fn) * 2) + kk) * 1024 + lane * 16);
                #pragma unroll
                for (int fm = 0; fm < 4; ++fm) {
                    const short8 af = *reinterpret_cast<const short8*>(
                        ldsA + (((wm * 4 + fm) * 8) + ks * 2 + kk) * 1024 + lane * 16);
                    #pragma unroll
                    for (int fn = 0; fn < 4; ++fn)
                        acc[fm][fn] = __builtin_amdgcn_mfma_f32_16x16x32_bf16(af, bfr[fn], acc[fm][fn], 0, 0, 0);
                }
            }
            __syncthreads();
        }

        // ---- epilogue (dedicated scratch; B prefetch in flight untouched) ----
        if (tid == 0) *lcnt = 0u;
        const int cbase = col0 + wn * 64;
        float e2c[4];
        #pragma unroll
        for (int fn = 0; fn < 4; ++fn) e2c[fn] = e2g[cbase + fn * 16 + llo];

        // pass 1: per-row min over this wave's 64-col quarter
        #pragma unroll
        for (int fm = 0; fm < 4; ++fm) {
            #pragma unroll
            for (int rg = 0; rg < 4; ++rg) {
                const int rl_ = wm * 64 + fm * 16 + lhi * 4 + rg;
                const float z2v = z2r[fm][rg];
                float m = z2v + e2c[0] - 2.0f * acc[fm][0][rg];
                #pragma unroll
                for (int fn = 1; fn < 4; ++fn)
                    m = fminf(m, z2v + e2c[fn] - 2.0f * acc[fm][fn][rg]);
                #pragma unroll
                for (int off = 1; off < 16; off <<= 1) m = fminf(m, __shfl_xor(m, off));
                if (llo == 0) rowmin[wn * 128 + rl_] = m;
            }
        }
        __syncthreads();
        if (tid < 128) {
            float m2 = rowmin[tid];
            #pragma unroll
            for (int q = 1; q < 4; ++q) m2 = fminf(m2, rowmin[q * 128 + tid]);
            const unsigned cur = amin[row0 + tid];
            unsigned old = cur;
            if (__float_as_uint(m2) < cur) old = atomicMin(&amin[row0 + tid], __float_as_uint(m2));
            thrbuf[tid] = fminf(__uint_as_float(old), m2) + MARGIN;
        }
        __syncthreads();

        // pass 2: emit candidates
        #pragma unroll
        for (int fm = 0; fm < 4; ++fm) {
            #pragma unroll
            for (int rg = 0; rg < 4; ++rg) {
                const int rl_ = wm * 64 + fm * 16 + lhi * 4 + rg;
                const int grow = row0 + rl_;
                const float z2v = z2r[fm][rg];
                const float thr = thrbuf[rl_];
                #pragma unroll
                for (int fn = 0; fn < 4; ++fn) {
                    const float d = z2v + e2c[fn] - 2.0f * acc[fm][fn][rg];
                    if (d <= thr) {
                        const unsigned v = ((unsigned)grow << 13) | (unsigned)(cbase + fn * 16 + llo);
                        const unsigned slot = atomicAdd(lcnt, 1u);
                        if (slot < BLKLIST) llist[slot] = v;
                        else exact_rescore(z, cbp, z2g, e2g, grow, v & 8191u, best);
                    }
                }
            }
        }
        __syncthreads();
        const unsigned bc = min(*lcnt, (unsigned)BLKLIST);
        if (tid == 0 && bc) gbase_s = atomicAdd(counter, bc);
        __syncthreads();
        for (unsigned i = tid; i < bc; i += 512) {
            const unsigned v = llist[i];
            const unsigned slot = gbase_s + i;
            if (slot < C) list[slot] = v;
            else exact_rescore(z, cbp, z2g, e2g, (int)(v >> 13), (int)(v & 8191u), best);
        }
        __syncthreads();   // escr quiescent before next iter
    }
}

// ---------------- exact rescore of candidate list (wave per candidate) ----------------
__global__ __launch_bounds__(256) void k_rescore(
    const float* __restrict__ z, const float* __restrict__ cbp,
    const float* __restrict__ z2g, const float* __restrict__ e2g,
    const unsigned* __restrict__ list, const unsigned* __restrict__ counter, unsigned C,
    unsigned long long* best)
{
    const unsigned n = min(counter[0], C);
    const unsigned wid = (blockIdx.x * blockDim.x + threadIdx.x) >> 6;
    const unsigned nw = (gridDim.x * blockDim.x) >> 6;
    const int lane = threadIdx.x & 63;
    for (unsigned i = wid; i < n; i += nw) {
        const unsigned v = list[i];
        const unsigned row = v >> 13, col = v & 8191u;
        const float4 a = *reinterpret_cast<const float4*>(z + (size_t)row * DDIM + lane * 4);
        const float4 b = *reinterpret_cast<const float4*>(cbp + (size_t)col * DDIM + lane * 4);
        float s = fmaf(a.x, b.x, fmaf(a.y, b.y, fmaf(a.z, b.z, a.w * b.w)));
        #pragma unroll
        for (int off = 1; off < 64; off <<= 1) s += __shfl_xor(s, off);
        if (lane == 0) {
            const float de = z2g[row] + e2g[col] - 2.0f * s;
            const unsigned long long key =
                ((unsigned long long)__float_as_uint(de) << 32) | col;
            atomicMin(&best[row], key);
        }
    }
}

// ---------------- gather + z_st + loss ----------------
__global__ __launch_bounds__(1024) void k_gather(
    const float* __restrict__ z, const float* __restrict__ cbp,
    const unsigned long long* __restrict__ best,
    float* __restrict__ out, float* __restrict__ accum)
{
    __shared__ float wsum[16];
    const int tid = threadIdx.x;
    const int row = blockIdx.x * 16 + (tid >> 6);
    const int lane = tid & 63;
    const unsigned k = (unsigned)(best[row] & 0xFFFFFFFFull);
    const float4 ze = *reinterpret_cast<const float4*>(z + (size_t)row * DDIM + lane * 4);
    const float4 cq = *reinterpret_cast<const float4*>(cbp + (size_t)k * DDIM + lane * 4);
    float4 zst;
    zst.x = ze.x + (cq.x - ze.x); zst.y = ze.y + (cq.y - ze.y);
    zst.z = ze.z + (cq.z - ze.z); zst.w = ze.w + (cq.w - ze.w);
    *reinterpret_cast<float4*>(out + (size_t)row * DDIM + lane * 4) = zst;
    const float dx = cq.x - ze.x, dy = cq.y - ze.y, dz = cq.z - ze.z, dw = cq.w - ze.w;
    float s = dx * dx + dy * dy + dz * dz + dw * dw;
    #pragma unroll
    for (int off = 32; off > 0; off >>= 1) s += __shfl_down(s, off);
    if (lane == 0) {
        wsum[tid >> 6] = s;
        out[(size_t)NROWS * DDIM + row] = (float)k;
    }
    __syncthreads();
    if (tid == 0) {
        float tot = 0.f;
        #pragma unroll
        for (int i = 0; i < 16; ++i) tot += wsum[i];
        atomicAdd(accum, tot);
    }
}

// ---------------- final scalars ----------------
__global__ void k_final(const float* __restrict__ accum, float* __restrict__ out) {
    const float m = accum[0] / (float)(NROWS * DDIM);
    out[(size_t)NROWS * DDIM + NROWS + 0] = m;
    out[(size_t)NROWS * DDIM + NROWS + 1] = m;
}

extern "C" void kernel_launch(void* const* d_in, const int* in_sizes, int n_in,
                              void* d_out, int out_size, void* d_ws, size_t ws_size,
                              hipStream_t stream)
{
    const float* z  = (const float*)d_in[0];
    const float* cb = (const float*)d_in[1];
    float* out = (float*)d_out;

    // bf16 pre-tiled scratch lives in d_out's z_st region (12 MB of 16.8 MB),
    // consumed by k_screen and fully overwritten afterwards by k_gather.
    unsigned short* z_t  = (unsigned short*)d_out;                      // 8 MB
    unsigned short* cb_t = (unsigned short*)((char*)d_out + 8388608);   // 4 MB

    char* ws = (char*)d_ws;
    unsigned long long* best = (unsigned long long*)ws;            // 131072 B
    unsigned* amin = (unsigned*)(ws + 131072);                     // 65536 B
    float* e2    = (float*)(ws + 131072 + 65536);                  // 32768 B
    float* z2    = (float*)(ws + 131072 + 65536 + 32768);          // 65536 B
    float* accum   = (float*)(ws + 294912);
    unsigned* counter = (unsigned*)(ws + 294916);
    unsigned* list = (unsigned*)(ws + 295936);
    unsigned C = 0;
    if (ws_size > 295936 + 16) {
        size_t c = (ws_size - 295936) / 4;
        if (c > 4194304) c = 4194304;
        C = (unsigned)c;
    }

    k_convert<<<NROWS / 16 / 4, 256, 0, stream>>>(z, z_t, z2, NROWS / 16, best, amin, accum, counter);
    k_convert<<<KCODES / 16 / 4, 256, 0, stream>>>(cb, cb_t, e2, KCODES / 16, nullptr, nullptr, nullptr, nullptr);
    k_screen<<<256, 512, 0, stream>>>(z, cb, z_t, cb_t, z2, e2, amin, best, counter, list, C);
    k_rescore<<<1024, 256, 0, stream>>>(z, cb, z2, e2, list, counter, C, best);
    k_gather<<<NROWS / 16, 1024, 0, stream>>>(z, cb, best, out, accum);
    k_final<<<1, 1, 0, stream>>>(accum, out);
}